// Round 1
// baseline (857.139 us; speedup 1.0000x reference)
//
#include <hip/hip_runtime.h>
#include <hip/hip_bf16.h>
#include <stdint.h>

// BatchedLoRALinear: out[m][o] = sum_k x[m][k] W[o][k] + b[o] + 2 * sum_r Bb[o][r] inter[m][r]
// m = b*512+s, M=16384, N=D_OUT=4096, K=D_IN=4096, R=16, N_ADAPT=32.
// Strategy: bf16 MFMA GEMM (m97 structure); LoRA folded in as one extra K-step.

typedef __attribute__((ext_vector_type(8))) short bf16x8;
typedef __attribute__((ext_vector_type(4))) float f32x4;
typedef __attribute__((ext_vector_type(8))) unsigned short ushort8;

#define MM    16384
#define DIN   4096
#define DOUT  4096
#define RR    16
#define NAD   32

__device__ __forceinline__ unsigned short f2bf(float f) {
    union { float f; unsigned int u; } v; v.f = f;
    unsigned int r = (v.u + 0x7FFFu + ((v.u >> 16) & 1u)) >> 16;  // RNE
    return (unsigned short)r;
}

__device__ __forceinline__ void gld16(const void* g, void* l) {
    __builtin_amdgcn_global_load_lds(
        (const __attribute__((address_space(1))) void*)g,
        (__attribute__((address_space(3))) void*)l,
        16, 0, 0);
}

// ---------- fp32 -> bf16 bulk convert (n % 8 == 0) ----------
__global__ __launch_bounds__(256) void cvt_kernel(const float* __restrict__ src,
                                                  unsigned short* __restrict__ dst,
                                                  long n) {
    long i0 = ((long)blockIdx.x * 256 + threadIdx.x) * 8;
    long stride = (long)gridDim.x * 256 * 8;
    for (long i = i0; i < n; i += stride) {
        float4 f0 = *(const float4*)(src + i);
        float4 f1 = *(const float4*)(src + i + 4);
        ushort8 o;
        o[0] = f2bf(f0.x); o[1] = f2bf(f0.y); o[2] = f2bf(f0.z); o[3] = f2bf(f0.w);
        o[4] = f2bf(f1.x); o[5] = f2bf(f1.y); o[6] = f2bf(f1.z); o[7] = f2bf(f1.w);
        *(ushort8*)(dst + i) = o;
    }
}

// ---------- B_all (NAD,DOUT,16) fp32 -> bf16 padded [NAD][DOUT][32] (cols 16..31 = 0) ----------
__global__ __launch_bounds__(256) void cvt_ball_kernel(const float* __restrict__ Ball,
                                                       unsigned short* __restrict__ Bbf) {
    int row = blockIdx.x * 256 + threadIdx.x;   // 0 .. NAD*DOUT-1 = 131071
    const float* s = Ball + (size_t)row * RR;
    ushort8 o0, o1, z;
    #pragma unroll
    for (int j = 0; j < 8; ++j) { o0[j] = f2bf(s[j]); o1[j] = f2bf(s[8 + j]); z[j] = 0; }
    ushort8* d = (ushort8*)(Bbf + (size_t)row * 32);
    d[0] = o0; d[1] = o1; d[2] = z; d[3] = z;
}

// ---------- inter[m][r] = 2 * sum_k x[m][k] * A_b[r][k], bf16, padded to 32 cols ----------
// one wave per 16 rows; skinny MFMA GEMM with N=16 (single fragment col).
__global__ __launch_bounds__(256) void inter_kernel(const unsigned short* __restrict__ Xbf,
                                                    const unsigned short* __restrict__ Abf,
                                                    const int* __restrict__ ids,
                                                    unsigned short* __restrict__ Ibf) {
    int tid = threadIdx.x, w = tid >> 6, lane = tid & 63;
    int m0 = blockIdx.x * 64 + w * 16;          // grid 256 blocks -> covers 16384 rows
    int aid = ids[m0 >> 9];                     // 512 rows per batch; block stays in-batch
    int lr = lane & 15, lk = (lane >> 4) * 8;
    const unsigned short* xp = Xbf + (size_t)(m0 + lr) * DIN + lk;
    const unsigned short* ap = Abf + ((size_t)aid * RR + lr) * DIN + lk;
    f32x4 acc = {};
    #pragma unroll 4
    for (int k = 0; k < DIN; k += 32) {
        bf16x8 a  = *(const bf16x8*)(xp + k);
        bf16x8 bb = *(const bf16x8*)(ap + k);
        acc = __builtin_amdgcn_mfma_f32_16x16x32_bf16(a, bb, acc, 0, 0, 0);
    }
    // D layout: col = lane&15, row = (lane>>4)*4 + reg
    int rbase = m0 + (lane >> 4) * 4;
    #pragma unroll
    for (int r = 0; r < 4; ++r) {
        int m = rbase + r;
        Ibf[(size_t)m * 32 + lr]      = f2bf(acc[r] * 2.0f);  // SCALING folded here
        Ibf[(size_t)m * 32 + 16 + lr] = 0;                    // zero-pad cols 16..31
    }
}

// ---------- main GEMM: 128x128 tile, BK=32, 4 waves (2x2) each 64x64, m97 structure ----------
__global__ __launch_bounds__(256) void gemm_kernel(const unsigned short* __restrict__ Xbf,
                                                   const unsigned short* __restrict__ Wbf,
                                                   const unsigned short* __restrict__ Ibf,
                                                   const unsigned short* __restrict__ Bbf,
                                                   const float* __restrict__ bias,
                                                   const int* __restrict__ ids,
                                                   float* __restrict__ out) {
    __shared__ alignas(16) unsigned short As[128 * 32];
    __shared__ alignas(16) unsigned short Bs[128 * 32];

    int tid = threadIdx.x;
    // XCD-aware swizzle: grid 4096 = 128(bm) x 32(bn), 4096 % 8 == 0 -> bijective
    int bid = blockIdx.x;
    int swz = (bid & 7) * 512 + (bid >> 3);
    int bm = swz >> 5, bn = swz & 31;
    int m0 = bm << 7, n0 = bn << 7;

    int w = tid >> 6, lane = tid & 63;
    int wr = w >> 1, wc = w & 1;
    int lr = lane & 15, lk8 = (lane >> 4) * 8;

    // staging map: thread tid loads 16B; idx -> row = idx/4, col elem = (idx%4)*8
    int srow = tid >> 2;
    int scol = (tid & 3) * 8;
    const unsigned short* xa = Xbf + (size_t)(m0 + srow) * DIN + scol;
    const unsigned short* xb = xa + (size_t)64 * DIN;
    const unsigned short* wa = Wbf + (size_t)(n0 + srow) * DIN + scol;
    const unsigned short* wb = wa + (size_t)64 * DIN;
    unsigned short* lA0 = &As[tid * 8];
    unsigned short* lA1 = &As[2048 + tid * 8];
    unsigned short* lB0 = &Bs[tid * 8];
    unsigned short* lB1 = &Bs[2048 + tid * 8];

    f32x4 acc[4][4] = {};

    for (int k = 0; k < DIN; k += 32) {
        gld16(xa + k, lA0);
        gld16(xb + k, lA1);
        gld16(wa + k, lB0);
        gld16(wb + k, lB1);
        __syncthreads();   // compiler drains vmcnt before barrier -> tiles visible
        bf16x8 af[4], bfr[4];
        #pragma unroll
        for (int f = 0; f < 4; ++f) {
            af[f]  = *(const bf16x8*)&As[(wr * 64 + f * 16 + lr) * 32 + lk8];
            bfr[f] = *(const bf16x8*)&Bs[(wc * 64 + f * 16 + lr) * 32 + lk8];
        }
        #pragma unroll
        for (int i = 0; i < 4; ++i)
            #pragma unroll
            for (int j = 0; j < 4; ++j)
                acc[i][j] = __builtin_amdgcn_mfma_f32_16x16x32_bf16(af[i], bfr[j], acc[i][j], 0, 0, 0);
        __syncthreads();   // all waves done reading before next stage overwrites
    }

    // ---- LoRA K-extension step: A-tile = inter (scaled, padded), B-tile = Bb (padded) ----
    {
        int aid = ids[m0 >> 9];
        const unsigned short* ia  = Ibf + (size_t)(m0 + srow) * 32 + scol;
        const unsigned short* ib  = ia + 64 * 32;
        const unsigned short* ba  = Bbf + ((size_t)aid * DOUT + n0 + srow) * 32 + scol;
        const unsigned short* bb2 = ba + 64 * 32;
        gld16(ia, lA0);
        gld16(ib, lA1);
        gld16(ba, lB0);
        gld16(bb2, lB1);
        __syncthreads();
        bf16x8 af[4], bfr[4];
        #pragma unroll
        for (int f = 0; f < 4; ++f) {
            af[f]  = *(const bf16x8*)&As[(wr * 64 + f * 16 + lr) * 32 + lk8];
            bfr[f] = *(const bf16x8*)&Bs[(wc * 64 + f * 16 + lr) * 32 + lk8];
        }
        #pragma unroll
        for (int i = 0; i < 4; ++i)
            #pragma unroll
            for (int j = 0; j < 4; ++j)
                acc[i][j] = __builtin_amdgcn_mfma_f32_16x16x32_bf16(af[i], bfr[j], acc[i][j], 0, 0, 0);
    }

    // ---- epilogue: + bias, write fp32. C/D layout: col = lane&15, row = (lane>>4)*4+reg ----
    float bv[4];
    #pragma unroll
    for (int fj = 0; fj < 4; ++fj) bv[fj] = bias[n0 + wc * 64 + fj * 16 + lr];
    int rbase = m0 + wr * 64 + (lane >> 4) * 4;
    #pragma unroll
    for (int fi = 0; fi < 4; ++fi) {
        #pragma unroll
        for (int fj = 0; fj < 4; ++fj) {
            int col = n0 + wc * 64 + fj * 16 + lr;
            #pragma unroll
            for (int r = 0; r < 4; ++r) {
                out[(size_t)(rbase + fi * 16 + r) * DOUT + col] = acc[fi][fj][r] + bv[fj];
            }
        }
    }
}

extern "C" void kernel_launch(void* const* d_in, const int* in_sizes, int n_in,
                              void* d_out, int out_size, void* d_ws, size_t ws_size,
                              hipStream_t stream) {
    const float* x     = (const float*)d_in[0];   // (32,512,4096)
    const int*   ids   = (const int*)d_in[1];     // (32,)
    const float* A_all = (const float*)d_in[2];   // (32,16,4096)
    const float* B_all = (const float*)d_in[3];   // (32,4096,16)
    const float* W     = (const float*)d_in[4];   // (4096,4096)
    const float* bias  = (const float*)d_in[5];   // (4096,)
    float* out = (float*)d_out;                   // (32,512,4096) fp32

    // workspace layout (elems of unsigned short). total = 181,403,648 bytes
    unsigned short* Xbf = (unsigned short*)d_ws;             // [16384][4096]
    unsigned short* Wbf = Xbf + (size_t)MM * DIN;            // [4096][4096]
    unsigned short* Abf = Wbf + (size_t)DOUT * DIN;          // [32][16][4096]
    unsigned short* Bbf = Abf + (size_t)NAD * RR * DIN;      // [32][4096][32] padded
    unsigned short* Ibf = Bbf + (size_t)NAD * DOUT * 32;     // [16384][32] padded

    cvt_kernel<<<8192, 256, 0, stream>>>(x, Xbf, (long)MM * DIN);
    cvt_kernel<<<8192, 256, 0, stream>>>(W, Wbf, (long)DOUT * DIN);
    cvt_kernel<<<1024, 256, 0, stream>>>(A_all, Abf, (long)NAD * RR * DIN);
    cvt_ball_kernel<<<512, 256, 0, stream>>>(B_all, Bbf);
    inter_kernel<<<256, 256, 0, stream>>>(Xbf, Abf, ids, Ibf);
    gemm_kernel<<<4096, 256, 0, stream>>>(Xbf, Wbf, Ibf, Bbf, bias, ids, out);
}